// Round 8
// baseline (893.554 us; speedup 1.0000x reference)
//
#include <hip/hip_runtime.h>
#include <hip/hip_fp16.h>
#include <cstddef>

// StackLSTM: T=64, B=128, H=256, L=2.  ops∈{0,1} => stack never pops:
// top-of-stack = h(last push step), maintained by gated update.
//
// Round-8: r7 tagged-dataflow exchange (proven) + 4 WGs/CU (1024 WGs, 2 batch
// elems each, all co-resident) + conflict-free strided k-slicing for LDS.
#define TT 64
#define BB 128
#define HH 256
#define G4 1024
#define BLK 256
#define NBG 64
#define NHG 16

// ws float-slot offsets
#define OFF_XG     0u          // [64 t][16 hg][128 b][64 lc] fp32 = 8,388,608
#define OFF_WTIH0  8388608u    // [256][1024] fp32 W_ih[0]^T (for xg) = 262,144
#define OFF_HX0    8650752u    // u64 [2 par][64 bg][2 b][128 k2] = 65,536 floats
#define OFF_HX1    8716288u    // same
// total 8,781,824 floats = 35.1 MB

__device__ __forceinline__ float sigf(float x) { return 1.0f / (1.0f + expf(-x)); }

typedef _Float16 h2v __attribute__((ext_vector_type(2)));

__device__ __forceinline__ float dot2acc(unsigned w, unsigned h, float acc) {
#if __has_builtin(__builtin_amdgcn_fdot2)
  return __builtin_amdgcn_fdot2(__builtin_bit_cast(h2v, w),
                                __builtin_bit_cast(h2v, h), acc, false);
#else
  __half2 wv = *(__half2*)&w, hv = *(__half2*)&h;
  float2 wf = __half22float2(wv), hf = __half22float2(hv);
  return fmaf(wf.x, hf.x, fmaf(wf.y, hf.y, acc));
#endif
}

__device__ __forceinline__ unsigned packh2(float e, float o) {
  return (unsigned)__half_as_ushort(__float2half(e)) |
         ((unsigned)__half_as_ushort(__float2half(o)) << 16);
}

// ---------------------------------------------------------------------------
// transpose W_ih[0] [1024][256] -> [256][1024] fp32 (for xg_kernel)
// ---------------------------------------------------------------------------
__global__ void transpose1(const float* __restrict__ W_ih, float* __restrict__ ws) {
  __shared__ float tile[32][33];
  float* dst = ws + OFF_WTIH0;
  const int g0 = blockIdx.x * 32, k0 = blockIdx.y * 32;
  const int tx = threadIdx.x, ty = threadIdx.y;
#pragma unroll
  for (int i = 0; i < 32; i += 8)
    tile[ty + i][tx] = W_ih[(size_t)(g0 + ty + i) * HH + k0 + tx];
  __syncthreads();
#pragma unroll
  for (int i = 0; i < 32; i += 8)
    dst[(size_t)(k0 + ty + i) * G4 + g0 + tx] = tile[tx][ty + i];
}

// ---------------------------------------------------------------------------
// Xg[t][hg][b][lc] = b_ih0[g] + x[t,b,:] @ W_ih0[g,:]   (fp32, exact)
// g = (lc>>4)*256 + hg*16 + (lc&15)
// ---------------------------------------------------------------------------
__global__ void xg_kernel(const float* __restrict__ x,
                          const float* __restrict__ b_ih,
                          float* __restrict__ ws) {
  const float* __restrict__ WTih0 = ws + OFF_WTIH0;
  float* __restrict__ Xg = ws + OFF_XG;
  const int r0 = blockIdx.x * 16;
  const int g = blockIdx.y * 256 + threadIdx.x;
  __shared__ float xs[16][HH];
  for (int i = threadIdx.x; i < 16 * HH; i += 256)
    xs[i >> 8][i & 255] = x[(size_t)(r0 + (i >> 8)) * HH + (i & 255)];
  __syncthreads();
  float acc[16];
  const float bias = b_ih[g];
#pragma unroll
  for (int r = 0; r < 16; ++r) acc[r] = bias;
  for (int k = 0; k < HH; ++k) {
    const float w = WTih0[(size_t)k * G4 + g];
#pragma unroll
    for (int r = 0; r < 16; ++r) acc[r] = fmaf(xs[r][k], w, acc[r]);
  }
  const int hg = (g >> 4) & 15;
  const int lc = ((g >> 8) << 4) | (g & 15);
#pragma unroll
  for (int r = 0; r < 16; ++r) {
    const int rr = r0 + r;
    const int t = rr >> 7, b = rr & 127;
    Xg[(((size_t)t * NHG + hg) * 128 + b) * 64 + lc] = acc[r];
  }
}

// ---------------------------------------------------------------------------
// Sequential recurrence: register weights + tagged dataflow, 4 WGs/CU.
// Thread (c2 = tid>>3, kq = tid&7): cols {2c2, 2c2+1}, k2 slice
// {s*32 + kq*4 + i : s in 0..3, i in 0..3} (bank-conflict-free b128 reads).
// ---------------------------------------------------------------------------
__global__ void __launch_bounds__(BLK, 4)
seq8(const float* __restrict__ W_ih,
     const float* __restrict__ W_hh,
     const float* __restrict__ b_ih,
     const float* __restrict__ b_hh,
     const int* __restrict__ ops,
     float* __restrict__ ws,
     float* __restrict__ out) {
  const int bg = blockIdx.x & 63;     // batch group (2 b); exchange group = bg
  const int hg = blockIdx.x >> 6;     // 0..15 (members stride 64 -> same XCD)
  const int tid = threadIdx.x;
  const int kq = tid & 7;
  const int c2 = tid >> 3;            // 0..31

  __shared__ float XgL[TT * 128];     // 32 KB [t][2 b][64 lc]
  __shared__ unsigned hp0[256];       // [2 b][128 k2] f16-pair gated h0
  __shared__ unsigned hp1[256];
  __shared__ unsigned h0c[256];       // raw h0(t), layer-1 input
  __shared__ float gat[128];          // [2 b][64 lc]
  __shared__ int opsA[TT * 2];        // [t][b]

  // ---- prologue: weights -> VGPRs (f16 pairs, strided-k layout) ----
  unsigned wr0[32], wr1[32], wr2[32];
  {
    const float* s0 = W_hh;                       // W_hh[0]
    const float* s1 = W_ih + (size_t)G4 * HH;     // W_ih[1]
    const float* s2 = W_hh + (size_t)G4 * HH;     // W_hh[1]
#pragma unroll
    for (int j = 0; j < 2; ++j) {
      const int lc = c2 * 2 + j;
      const int g = ((lc >> 4) << 8) + hg * 16 + (lc & 15);
#pragma unroll
      for (int s = 0; s < 4; ++s)
#pragma unroll
        for (int i = 0; i < 4; ++i) {
          const int k2 = s * 32 + kq * 4 + i;
          const float* p0 = s0 + (size_t)g * HH + 2 * k2;
          const float* p1 = s1 + (size_t)g * HH + 2 * k2;
          const float* p2 = s2 + (size_t)g * HH + 2 * k2;
          wr0[j * 16 + s * 4 + i] = packh2(p0[0], p0[1]);
          wr1[j * 16 + s * 4 + i] = packh2(p1[0], p1[1]);
          wr2[j * 16 + s * 4 + i] = packh2(p2[0], p2[1]);
        }
    }
  }
  float bias0r[2], bias1r[2];
#pragma unroll
  for (int j = 0; j < 2; ++j) {
    const int lc = c2 * 2 + j;
    const int g = ((lc >> 4) << 8) + hg * 16 + (lc & 15);
    bias0r[j] = b_hh[g];                           // b_ih0 folded into Xg
    bias1r[j] = b_ih[G4 + g] + b_hh[G4 + g];
  }
  for (int i = tid; i < TT * 32; i += BLK) {       // 2048 float4
    const int t = i >> 5, r = i & 31;
    ((float4*)XgL)[i] = *(const float4*)(
        ws + OFF_XG + (((size_t)t * NHG + hg) * 128 + bg * 2) * 64 + r * 4);
  }
  for (int i = tid; i < TT * 2; i += BLK)
    opsA[i] = ops[(i >> 1) * BB + bg * 2 + (i & 1)];
  for (int i = tid; i < 256; i += BLK) { hp0[i] = 0u; hp1[i] = 0u; }

  unsigned long long* __restrict__ Hx0 = (unsigned long long*)(ws + OFF_HX0);
  unsigned long long* __restrict__ Hx1 = (unsigned long long*)(ws + OFF_HX1);
  float cp0 = 0.f, cp1 = 0.f;         // cell state, held by tid<32
  __syncthreads();

  for (int t = 0; t < TT; ++t) {
    const int par = t & 1;

    // ---- layer-0 dots: wr0 . hp0 ----
    float a0[2][2];
#pragma unroll
    for (int b = 0; b < 2; ++b) {
      const uint4 x0 = *(const uint4*)&hp0[b * 128 + 0 * 32 + kq * 4];
      const uint4 x1 = *(const uint4*)&hp0[b * 128 + 1 * 32 + kq * 4];
      const uint4 x2 = *(const uint4*)&hp0[b * 128 + 2 * 32 + kq * 4];
      const uint4 x3 = *(const uint4*)&hp0[b * 128 + 3 * 32 + kq * 4];
      const unsigned hh[16] = {x0.x, x0.y, x0.z, x0.w, x1.x, x1.y, x1.z, x1.w,
                               x2.x, x2.y, x2.z, x2.w, x3.x, x3.y, x3.z, x3.w};
#pragma unroll
      for (int j = 0; j < 2; ++j) {
        float a = 0.f;
#pragma unroll
        for (int i = 0; i < 16; ++i) a = dot2acc(wr0[j * 16 + i], hh[i], a);
        a0[b][j] = a;
      }
    }
#pragma unroll
    for (int m = 1; m <= 4; m <<= 1)
#pragma unroll
      for (int b = 0; b < 2; ++b) {
        a0[b][0] += __shfl_xor(a0[b][0], m, 64);
        a0[b][1] += __shfl_xor(a0[b][1], m, 64);
      }
    if (kq == 0) {
#pragma unroll
      for (int b = 0; b < 2; ++b)
        *(float2*)&gat[b * 64 + c2 * 2] =
            make_float2(a0[b][0] + bias0r[0], a0[b][1] + bias0r[1]);
    }
    __syncthreads();

    // ---- cell 0 + tagged publish of h0 ----
    if (tid < 32) {
      const int b = tid >> 4, r = tid & 15;
      const float* xg = &XgL[t * 128 + b * 64];
      const float* gt = &gat[b * 64];
      const float ig = gt[r] + xg[r],           fg = gt[16 + r] + xg[16 + r];
      const float gg = gt[32 + r] + xg[32 + r], og = gt[48 + r] + xg[48 + r];
      const float c = sigf(fg) * cp0 + sigf(ig) * tanhf(gg);
      const float h = sigf(og) * tanhf(c);
      if (opsA[t * 2 + b]) cp0 = c;
      const float ho = __shfl_xor(h, 1, 64);
      if (!(r & 1)) {
        const unsigned long long v =
            (unsigned long long)(unsigned)(t + 1) |
            ((unsigned long long)packh2(h, ho) << 32);
        __hip_atomic_store(
            Hx0 + ((size_t)par * NBG + bg) * 256 + b * 128 + hg * 8 + (r >> 1),
            v, __ATOMIC_RELAXED, __HIP_MEMORY_SCOPE_AGENT);
      }
    }
    // no barrier: merge polls below self-synchronize on tags

    // ---- merge: poll h1(t-1) first (older, likely ready), then h0(t) ----
    {
      const int b = tid >> 7, k2 = tid & 127;
      if (t > 0) {
        const unsigned long long* s1 = Hx1 + ((size_t)(par ^ 1) * NBG + bg) * 256;
        const unsigned tagB = (unsigned)t;
        unsigned long long v;
        int spins = 0;
        for (;;) {
          v = __hip_atomic_load(s1 + tid, __ATOMIC_RELAXED,
                                __HIP_MEMORY_SCOPE_AGENT);
          if ((unsigned)v == tagB) break;
          if (++spins > (1 << 18)) break;  // fail loudly instead of hanging
          __builtin_amdgcn_s_sleep(1);
        }
        if (opsA[(t - 1) * 2 + b]) hp1[b * 128 + k2] = (unsigned)(v >> 32);
      }
      {
        const unsigned long long* s0 = Hx0 + ((size_t)par * NBG + bg) * 256;
        const unsigned tagA = (unsigned)(t + 1);
        unsigned long long v;
        int spins = 0;
        for (;;) {
          v = __hip_atomic_load(s0 + tid, __ATOMIC_RELAXED,
                                __HIP_MEMORY_SCOPE_AGENT);
          if ((unsigned)v == tagA) break;
          if (++spins > (1 << 18)) break;
          __builtin_amdgcn_s_sleep(1);
        }
        const unsigned pay = (unsigned)(v >> 32);
        h0c[b * 128 + k2] = pay;
        if (opsA[t * 2 + b]) hp0[b * 128 + k2] = pay;
      }
    }
    __syncthreads();

    // ---- layer-1 dots: wr1 . h0c + wr2 . hp1 ----
    float a1[2][2];
#pragma unroll
    for (int b = 0; b < 2; ++b) {
      const uint4 c0 = *(const uint4*)&h0c[b * 128 + 0 * 32 + kq * 4];
      const uint4 c1 = *(const uint4*)&h0c[b * 128 + 1 * 32 + kq * 4];
      const uint4 c2v = *(const uint4*)&h0c[b * 128 + 2 * 32 + kq * 4];
      const uint4 c3 = *(const uint4*)&h0c[b * 128 + 3 * 32 + kq * 4];
      const uint4 q0 = *(const uint4*)&hp1[b * 128 + 0 * 32 + kq * 4];
      const uint4 q1 = *(const uint4*)&hp1[b * 128 + 1 * 32 + kq * 4];
      const uint4 q2 = *(const uint4*)&hp1[b * 128 + 2 * 32 + kq * 4];
      const uint4 q3 = *(const uint4*)&hp1[b * 128 + 3 * 32 + kq * 4];
      const unsigned hc[16] = {c0.x, c0.y, c0.z, c0.w, c1.x, c1.y, c1.z, c1.w,
                               c2v.x, c2v.y, c2v.z, c2v.w, c3.x, c3.y, c3.z, c3.w};
      const unsigned hq[16] = {q0.x, q0.y, q0.z, q0.w, q1.x, q1.y, q1.z, q1.w,
                               q2.x, q2.y, q2.z, q2.w, q3.x, q3.y, q3.z, q3.w};
#pragma unroll
      for (int j = 0; j < 2; ++j) {
        float a = 0.f;
#pragma unroll
        for (int i = 0; i < 16; ++i) {
          a = dot2acc(wr1[j * 16 + i], hc[i], a);
          a = dot2acc(wr2[j * 16 + i], hq[i], a);
        }
        a1[b][j] = a;
      }
    }
#pragma unroll
    for (int m = 1; m <= 4; m <<= 1)
#pragma unroll
      for (int b = 0; b < 2; ++b) {
        a1[b][0] += __shfl_xor(a1[b][0], m, 64);
        a1[b][1] += __shfl_xor(a1[b][1], m, 64);
      }
    if (kq == 0) {
#pragma unroll
      for (int b = 0; b < 2; ++b)
        *(float2*)&gat[b * 64 + c2 * 2] =
            make_float2(a1[b][0] + bias1r[0], a1[b][1] + bias1r[1]);
    }
    __syncthreads();

    // ---- cell 1: output + tagged publish of h1 ----
    if (tid < 32) {
      const int b = tid >> 4, r = tid & 15;
      const float* gt = &gat[b * 64];
      const float ig = gt[r],      fg = gt[16 + r];
      const float gg = gt[32 + r], og = gt[48 + r];
      const float c = sigf(fg) * cp1 + sigf(ig) * tanhf(gg);
      const float h = sigf(og) * tanhf(c);
      if (opsA[t * 2 + b]) cp1 = c;
      out[((size_t)t * BB + bg * 2 + b) * HH + hg * 16 + r] = h;
      const float ho = __shfl_xor(h, 1, 64);
      if (!(r & 1)) {
        const unsigned long long v =
            (unsigned long long)(unsigned)(t + 1) |
            ((unsigned long long)packh2(h, ho) << 32);
        __hip_atomic_store(
            Hx1 + ((size_t)par * NBG + bg) * 256 + b * 128 + hg * 8 + (r >> 1),
            v, __ATOMIC_RELAXED, __HIP_MEMORY_SCOPE_AGENT);
      }
    }
    __syncthreads();  // gat/hp reuse safety for next step
  }
}

// ---------------------------------------------------------------------------
extern "C" void kernel_launch(void* const* d_in, const int* in_sizes, int n_in,
                              void* d_out, int out_size, void* d_ws, size_t ws_size,
                              hipStream_t stream) {
  const float* x    = (const float*)d_in[0];
  const int*   ops  = (const int*)d_in[1];
  const float* W_ih = (const float*)d_in[2];
  const float* W_hh = (const float*)d_in[3];
  const float* b_ih = (const float*)d_in[4];
  const float* b_hh = (const float*)d_in[5];
  float* out = (float*)d_out;
  float* ws  = (float*)d_ws;

  transpose1<<<dim3(32, 8), dim3(32, 8), 0, stream>>>(W_ih, ws);
  xg_kernel<<<dim3(512, 4), 256, 0, stream>>>(x, b_ih, ws);
  seq8<<<1024, BLK, 0, stream>>>(W_ih, W_hh, b_ih, b_hh, ops, ws, out);
}

// Round 9
// 589.698 us; speedup vs baseline: 1.5153x; 1.5153x over previous
//
#include <hip/hip_runtime.h>
#include <hip/hip_fp16.h>
#include <cstddef>

// StackLSTM: T=64, B=128, H=256, L=2.  ops∈{0,1} => stack never pops:
// top-of-stack = h(last push step), maintained by gated update.
//
// Round-9: tagged-dataflow exchange (r7, proven) + 4 WGs/CU with a weight
// slice that actually fits registers: 1024 WGs = (bg 0..31 x hg 0..31),
// WG owns 4 b x 8 h-cols; thread (cc,kq) holds 1 gate-col x 16 k2-words
// per matrix = 48 weight VGPRs. No XgL staging (per-step 512B global load).
#define TT 64
#define BB 128
#define HH 256
#define G4 1024
#define BLK 256
#define NBG 32
#define NHG 32

// ws float-slot offsets
#define OFF_XG     0u          // [64 t][32 hg][128 b][32 lc] fp32 = 8,388,608
#define OFF_WTIH0  8388608u    // [256][1024] fp32 W_ih[0]^T (for xg) = 262,144
#define OFF_HX0    8650752u    // u64 [2 par][32 bg][4 b][128 k2] = 65,536 floats
#define OFF_HX1    8716288u    // same
// total 8,781,824 floats = 35.1 MB

__device__ __forceinline__ float sigf(float x) { return 1.0f / (1.0f + expf(-x)); }

typedef _Float16 h2v __attribute__((ext_vector_type(2)));

__device__ __forceinline__ float dot2acc(unsigned w, unsigned h, float acc) {
#if __has_builtin(__builtin_amdgcn_fdot2)
  return __builtin_amdgcn_fdot2(__builtin_bit_cast(h2v, w),
                                __builtin_bit_cast(h2v, h), acc, false);
#else
  __half2 wv = *(__half2*)&w, hv = *(__half2*)&h;
  float2 wf = __half22float2(wv), hf = __half22float2(hv);
  return fmaf(wf.x, hf.x, fmaf(wf.y, hf.y, acc));
#endif
}

__device__ __forceinline__ unsigned packh2(float e, float o) {
  return (unsigned)__half_as_ushort(__float2half(e)) |
         ((unsigned)__half_as_ushort(__float2half(o)) << 16);
}

// ---------------------------------------------------------------------------
// transpose W_ih[0] [1024][256] -> [256][1024] fp32 (for xg_kernel)
// ---------------------------------------------------------------------------
__global__ void transpose1(const float* __restrict__ W_ih, float* __restrict__ ws) {
  __shared__ float tile[32][33];
  float* dst = ws + OFF_WTIH0;
  const int g0 = blockIdx.x * 32, k0 = blockIdx.y * 32;
  const int tx = threadIdx.x, ty = threadIdx.y;
#pragma unroll
  for (int i = 0; i < 32; i += 8)
    tile[ty + i][tx] = W_ih[(size_t)(g0 + ty + i) * HH + k0 + tx];
  __syncthreads();
#pragma unroll
  for (int i = 0; i < 32; i += 8)
    dst[(size_t)(k0 + ty + i) * G4 + g0 + tx] = tile[tx][ty + i];
}

// ---------------------------------------------------------------------------
// Xg[t][hg][b][lc] = b_ih0[g] + x[t,b,:] @ W_ih0[g,:]   (fp32, exact)
// hg = (g>>3)&31, lc = (g>>8)*8 + (g&7)
// ---------------------------------------------------------------------------
__global__ void xg_kernel(const float* __restrict__ x,
                          const float* __restrict__ b_ih,
                          float* __restrict__ ws) {
  const float* __restrict__ WTih0 = ws + OFF_WTIH0;
  float* __restrict__ Xg = ws + OFF_XG;
  const int r0 = blockIdx.x * 16;
  const int g = blockIdx.y * 256 + threadIdx.x;
  __shared__ float xs[16][HH];
  for (int i = threadIdx.x; i < 16 * HH; i += 256)
    xs[i >> 8][i & 255] = x[(size_t)(r0 + (i >> 8)) * HH + (i & 255)];
  __syncthreads();
  float acc[16];
  const float bias = b_ih[g];
#pragma unroll
  for (int r = 0; r < 16; ++r) acc[r] = bias;
  for (int k = 0; k < HH; ++k) {
    const float w = WTih0[(size_t)k * G4 + g];
#pragma unroll
    for (int r = 0; r < 16; ++r) acc[r] = fmaf(xs[r][k], w, acc[r]);
  }
  const int hg = (g >> 3) & 31;
  const int lc = ((g >> 8) << 3) | (g & 7);
#pragma unroll
  for (int r = 0; r < 16; ++r) {
    const int rr = r0 + r;
    const int t = rr >> 7, b = rr & 127;
    Xg[(((size_t)t * NHG + hg) * 128 + b) * 32 + lc] = acc[r];
  }
}

// ---------------------------------------------------------------------------
// Sequential recurrence: 48 weight regs/thread, tagged dataflow, 4 WGs/CU.
// Thread (cc = tid>>3, kq = tid&7): col cc, k2 slice
// {s*32 + kq*4 + i : s in 0..3, i in 0..3} (bank-conflict-free b128 reads).
// ---------------------------------------------------------------------------
__global__ void __launch_bounds__(BLK, 4)
seq9(const float* __restrict__ W_ih,
     const float* __restrict__ W_hh,
     const float* __restrict__ b_ih,
     const float* __restrict__ b_hh,
     const int* __restrict__ ops,
     float* __restrict__ ws,
     float* __restrict__ out) {
  const int bg = blockIdx.x & 31;     // batch group (4 b); exchange group = bg
  const int hg = blockIdx.x >> 5;     // 0..31 (members stride 32 -> same XCD)
  const int tid = threadIdx.x;
  const int kq = tid & 7;
  const int cc = tid >> 3;            // 0..31: local gate col

  __shared__ unsigned hp0[512];       // [4 b][128 k2] f16-pair gated h0
  __shared__ unsigned hp1[512];
  __shared__ unsigned h0c[512];       // raw h0(t), layer-1 input
  __shared__ float gat[128];          // [4 b][32 lc]
  __shared__ float xgb[128];          // [4 b][32 lc]
  __shared__ int opsA[TT * 4];        // [t][b]

  // ---- prologue: weights -> VGPRs (f16 pairs, strided-k layout) ----
  unsigned wr0[16], wr1[16], wr2[16];
  const int g = ((cc >> 3) << 8) + hg * 8 + (cc & 7);
  {
    const float* s0 = W_hh;                       // W_hh[0]
    const float* s1 = W_ih + (size_t)G4 * HH;     // W_ih[1]
    const float* s2 = W_hh + (size_t)G4 * HH;     // W_hh[1]
#pragma unroll
    for (int s = 0; s < 4; ++s)
#pragma unroll
      for (int i = 0; i < 4; ++i) {
        const int k2 = s * 32 + kq * 4 + i;
        const float* p0 = s0 + (size_t)g * HH + 2 * k2;
        const float* p1 = s1 + (size_t)g * HH + 2 * k2;
        const float* p2 = s2 + (size_t)g * HH + 2 * k2;
        wr0[s * 4 + i] = packh2(p0[0], p0[1]);
        wr1[s * 4 + i] = packh2(p1[0], p1[1]);
        wr2[s * 4 + i] = packh2(p2[0], p2[1]);
      }
  }
  const float bias0 = b_hh[g];                     // b_ih0 folded into Xg
  const float bias1 = b_ih[G4 + g] + b_hh[G4 + g];
  for (int i = tid; i < TT * 4; i += BLK)
    opsA[i] = ops[(i >> 2) * BB + bg * 4 + (i & 3)];
  for (int i = tid; i < 512; i += BLK) { hp0[i] = 0u; hp1[i] = 0u; }

  unsigned long long* __restrict__ Hx0 = (unsigned long long*)(ws + OFF_HX0);
  unsigned long long* __restrict__ Hx1 = (unsigned long long*)(ws + OFF_HX1);
  float cp0 = 0.f, cp1 = 0.f;         // cell state, held by tid<32
  __syncthreads();

  for (int t = 0; t < TT; ++t) {
    const int par = t & 1;

    // ---- early Xg load (512 B/WG; hidden behind layer-0 dots) ----
    float xgv = 0.f;
    if (tid < 128)
      xgv = ws[OFF_XG + (((size_t)t * NHG + hg) * 128 + bg * 4 + (tid >> 5)) * 32 +
               (tid & 31)];

    // ---- layer-0 dots: wr0 . hp0 ----
    float a0[4];
#pragma unroll
    for (int b = 0; b < 4; ++b) {
      float a = 0.f;
#pragma unroll
      for (int s = 0; s < 4; ++s) {
        const uint4 hx = *(const uint4*)&hp0[b * 128 + s * 32 + kq * 4];
        a = dot2acc(wr0[s * 4 + 0], hx.x, a);
        a = dot2acc(wr0[s * 4 + 1], hx.y, a);
        a = dot2acc(wr0[s * 4 + 2], hx.z, a);
        a = dot2acc(wr0[s * 4 + 3], hx.w, a);
      }
      a0[b] = a;
    }
#pragma unroll
    for (int m = 1; m <= 4; m <<= 1)
#pragma unroll
      for (int b = 0; b < 4; ++b) a0[b] += __shfl_xor(a0[b], m, 64);
    if (kq == 0) {
#pragma unroll
      for (int b = 0; b < 4; ++b) gat[b * 32 + cc] = a0[b] + bias0;
    }
    if (tid < 128) xgb[tid] = xgv;
    __syncthreads();

    // ---- cell 0 + tagged publish of h0 ----
    if (tid < 32) {
      const int b = tid >> 3, r = tid & 7;
      const float* gt = &gat[b * 32];
      const float* xg = &xgb[b * 32];
      const float ig = gt[r] + xg[r],           fg = gt[8 + r] + xg[8 + r];
      const float gg = gt[16 + r] + xg[16 + r], og = gt[24 + r] + xg[24 + r];
      const float c = sigf(fg) * cp0 + sigf(ig) * tanhf(gg);
      const float h = sigf(og) * tanhf(c);
      if (opsA[t * 4 + b]) cp0 = c;
      const float ho = __shfl_xor(h, 1, 64);
      if (!(r & 1)) {
        const unsigned long long v =
            (unsigned long long)(unsigned)(t + 1) |
            ((unsigned long long)packh2(h, ho) << 32);
        __hip_atomic_store(
            Hx0 + ((size_t)par * NBG + bg) * 512 + b * 128 + hg * 4 + (r >> 1),
            v, __ATOMIC_RELAXED, __HIP_MEMORY_SCOPE_AGENT);
      }
    }
    // no barrier: merge polls below self-synchronize on tags

    // ---- merge: poll h1(t-1) first (older, likely ready), then h0(t) ----
#pragma unroll
    for (int i = 0; i < 2; ++i) {
      const int idx = tid + i * 256;
      const int b = idx >> 7, k2 = idx & 127;
      if (t > 0) {
        const unsigned long long* s1 = Hx1 + ((size_t)(par ^ 1) * NBG + bg) * 512;
        const unsigned tagB = (unsigned)t;
        unsigned long long v;
        int spins = 0;
        for (;;) {
          v = __hip_atomic_load(s1 + idx, __ATOMIC_RELAXED,
                                __HIP_MEMORY_SCOPE_AGENT);
          if ((unsigned)v == tagB) break;
          if (++spins > (1 << 18)) break;  // fail loudly instead of hanging
          __builtin_amdgcn_s_sleep(1);
        }
        if (opsA[(t - 1) * 4 + b]) hp1[b * 128 + k2] = (unsigned)(v >> 32);
      }
      {
        const unsigned long long* s0 = Hx0 + ((size_t)par * NBG + bg) * 512;
        const unsigned tagA = (unsigned)(t + 1);
        unsigned long long v;
        int spins = 0;
        for (;;) {
          v = __hip_atomic_load(s0 + idx, __ATOMIC_RELAXED,
                                __HIP_MEMORY_SCOPE_AGENT);
          if ((unsigned)v == tagA) break;
          if (++spins > (1 << 18)) break;
          __builtin_amdgcn_s_sleep(1);
        }
        const unsigned pay = (unsigned)(v >> 32);
        h0c[b * 128 + k2] = pay;
        if (opsA[t * 4 + b]) hp0[b * 128 + k2] = pay;
      }
    }
    __syncthreads();

    // ---- layer-1 dots: wr1 . h0c + wr2 . hp1 ----
    float a1[4];
#pragma unroll
    for (int b = 0; b < 4; ++b) {
      float a = 0.f;
#pragma unroll
      for (int s = 0; s < 4; ++s) {
        const uint4 hc = *(const uint4*)&h0c[b * 128 + s * 32 + kq * 4];
        const uint4 hq = *(const uint4*)&hp1[b * 128 + s * 32 + kq * 4];
        a = dot2acc(wr1[s * 4 + 0], hc.x, a);
        a = dot2acc(wr1[s * 4 + 1], hc.y, a);
        a = dot2acc(wr1[s * 4 + 2], hc.z, a);
        a = dot2acc(wr1[s * 4 + 3], hc.w, a);
        a = dot2acc(wr2[s * 4 + 0], hq.x, a);
        a = dot2acc(wr2[s * 4 + 1], hq.y, a);
        a = dot2acc(wr2[s * 4 + 2], hq.z, a);
        a = dot2acc(wr2[s * 4 + 3], hq.w, a);
      }
      a1[b] = a;
    }
#pragma unroll
    for (int m = 1; m <= 4; m <<= 1)
#pragma unroll
      for (int b = 0; b < 4; ++b) a1[b] += __shfl_xor(a1[b], m, 64);
    if (kq == 0) {
#pragma unroll
      for (int b = 0; b < 4; ++b) gat[b * 32 + cc] = a1[b] + bias1;
    }
    __syncthreads();

    // ---- cell 1: output + tagged publish of h1 ----
    if (tid < 32) {
      const int b = tid >> 3, r = tid & 7;
      const float* gt = &gat[b * 32];
      const float ig = gt[r],      fg = gt[8 + r];
      const float gg = gt[16 + r], og = gt[24 + r];
      const float c = sigf(fg) * cp1 + sigf(ig) * tanhf(gg);
      const float h = sigf(og) * tanhf(c);
      if (opsA[t * 4 + b]) cp1 = c;
      out[((size_t)t * BB + bg * 4 + b) * HH + hg * 8 + r] = h;
      const float ho = __shfl_xor(h, 1, 64);
      if (!(r & 1)) {
        const unsigned long long v =
            (unsigned long long)(unsigned)(t + 1) |
            ((unsigned long long)packh2(h, ho) << 32);
        __hip_atomic_store(
            Hx1 + ((size_t)par * NBG + bg) * 512 + b * 128 + hg * 4 + (r >> 1),
            v, __ATOMIC_RELAXED, __HIP_MEMORY_SCOPE_AGENT);
      }
    }
    __syncthreads();  // gat reuse safety for next step
  }
}

// ---------------------------------------------------------------------------
extern "C" void kernel_launch(void* const* d_in, const int* in_sizes, int n_in,
                              void* d_out, int out_size, void* d_ws, size_t ws_size,
                              hipStream_t stream) {
  const float* x    = (const float*)d_in[0];
  const int*   ops  = (const int*)d_in[1];
  const float* W_ih = (const float*)d_in[2];
  const float* W_hh = (const float*)d_in[3];
  const float* b_ih = (const float*)d_in[4];
  const float* b_hh = (const float*)d_in[5];
  float* out = (float*)d_out;
  float* ws  = (float*)d_ws;

  transpose1<<<dim3(32, 8), dim3(32, 8), 0, stream>>>(W_ih, ws);
  xg_kernel<<<dim3(512, 4), 256, 0, stream>>>(x, b_ih, ws);
  seq9<<<1024, BLK, 0, stream>>>(W_ih, W_hh, b_ih, b_hh, ops, ws, out);
}